// Round 1
// baseline (3276.870 us; speedup 1.0000x reference)
//
#include <hip/hip_runtime.h>
#include <math.h>

#define NSTACKC 4
#define FD 8
#define HD 64
#define KD 10
#define MD 29
#define TBF 4.0f

__device__ __forceinline__ float splus(float v) {
    // softplus: log1p(exp(v)), stable for large v
    return (v > 20.0f) ? v : log1pf(__expf(v));
}

__global__ __launch_bounds__(256) void nsf_fused_kernel(
    const float* __restrict__ X,
    const float* __restrict__ W0,
    const float* __restrict__ B0,
    const float* __restrict__ W1,
    const float* __restrict__ B1,
    const float* __restrict__ W2,
    const float* __restrict__ B2,
    float* __restrict__ OUT,
    int Bn)
{
    int b = blockIdx.x * blockDim.x + threadIdx.x;
    if (b >= Bn) return;

    float x[FD];
    {
        const float4* xp = (const float4*)(X + (size_t)b * FD);
        float4 v0 = xp[0];
        float4 v1 = xp[1];
        x[0] = v0.x; x[1] = v0.y; x[2] = v0.z; x[3] = v0.w;
        x[4] = v1.x; x[5] = v1.y; x[6] = v1.z; x[7] = v1.w;
    }

    for (int s = 0; s < NSTACKC; ++s) {
        const float* w0s = W0 + (size_t)s * FD * FD * HD;
        const float* b0s = B0 + (size_t)s * FD * HD;
        const float* w1s = W1 + (size_t)s * FD * HD * HD;
        const float* b1s = B1 + (size_t)s * FD * HD;
        const float* w2s = W2 + (size_t)s * FD * HD * MD;
        const float* b2s = B2 + (size_t)s * FD * MD;

        float y[FD];

        for (int i = 0; i < FD; ++i) {
            // ---- layer 1: masked 8 -> 64, relu ----
            float h1[HD];
            #pragma unroll
            for (int hh = 0; hh < HD; ++hh) h1[hh] = b0s[i * HD + hh];
            #pragma unroll
            for (int f = 0; f < FD; ++f) {
                if (f <= i) {  // uniform branch (i is a uniform loop counter)
                    float xf = x[f];
                    const float* wrow = w0s + ((size_t)i * FD + f) * HD;
                    #pragma unroll
                    for (int hh = 0; hh < HD; ++hh)
                        h1[hh] = fmaf(xf, wrow[hh], h1[hh]);
                }
            }
            #pragma unroll
            for (int hh = 0; hh < HD; ++hh) h1[hh] = fmaxf(h1[hh], 0.0f);

            // ---- layer 2: 64 -> 64 (relu folded into layer-3 read) ----
            float h2[HD];
            #pragma unroll
            for (int oo = 0; oo < HD; ++oo) h2[oo] = b1s[i * HD + oo];
            #pragma unroll
            for (int hh = 0; hh < HD; ++hh) {
                float hv = h1[hh];
                const float* wrow = w1s + ((size_t)i * HD + hh) * HD;
                #pragma unroll
                for (int oo = 0; oo < HD; ++oo)
                    h2[oo] = fmaf(hv, wrow[oo], h2[oo]);
            }

            // ---- layer 3: 64 -> 29 ----
            float p[MD];
            #pragma unroll
            for (int m = 0; m < MD; ++m) p[m] = b2s[i * MD + m];
            #pragma unroll
            for (int hh = 0; hh < HD; ++hh) {
                float hv = fmaxf(h2[hh], 0.0f);
                const float* wrow = w2s + ((size_t)i * HD + hh) * MD;
                #pragma unroll
                for (int m = 0; m < MD; ++m)
                    p[m] = fmaf(hv, wrow[m], p[m]);
            }

            // ---- rational-quadratic spline on feature i ----
            float xi = x[i];

            // widths: softmax(p[0:10]) -> affine -> cumsum -> bins
            float mw = p[0];
            #pragma unroll
            for (int k = 1; k < KD; ++k) mw = fmaxf(mw, p[k]);
            float ew[KD];
            float sw = 0.0f;
            #pragma unroll
            for (int k = 0; k < KD; ++k) { ew[k] = __expf(p[k] - mw); sw += ew[k]; }
            float invw = 1.0f / sw;
            float cw[KD + 1];
            cw[0] = -TBF;
            {
                float acc = 0.0f;
                #pragma unroll
                for (int k = 0; k < KD; ++k) {
                    float wk = 0.001f + (1.0f - 0.001f * KD) * ew[k] * invw;
                    acc += wk;
                    cw[k + 1] = 2.0f * TBF * acc - TBF;
                }
            }
            cw[KD] = TBF;

            // heights: softmax(p[10:20]) -> affine -> cumsum -> bins
            float mh = p[KD];
            #pragma unroll
            for (int k = 1; k < KD; ++k) mh = fmaxf(mh, p[KD + k]);
            float eh[KD];
            float sh = 0.0f;
            #pragma unroll
            for (int k = 0; k < KD; ++k) { eh[k] = __expf(p[KD + k] - mh); sh += eh[k]; }
            float invh = 1.0f / sh;
            float ch[KD + 1];
            ch[0] = -TBF;
            {
                float acc = 0.0f;
                #pragma unroll
                for (int k = 0; k < KD; ++k) {
                    float hk = 0.001f + (1.0f - 0.001f * KD) * eh[k] * invh;
                    acc += hk;
                    ch[k + 1] = 2.0f * TBF * acc - TBF;
                }
            }
            ch[KD] = TBF;

            // derivatives: d[0]=d[10]=MIN_D+softplus(const)==1.0 exactly
            float d[KD + 1];
            d[0] = 1.0f;
            d[KD] = 1.0f;
            #pragma unroll
            for (int k = 1; k < KD; ++k) d[k] = 0.001f + splus(p[2 * KD + (k - 1)]);

            float xc = fminf(fmaxf(xi, -TBF), TBF);

            // bin select: idx = last k in [0,9] with xc >= cw[k] (monotone cndmask chain)
            float w_b  = cw[1] - cw[0];
            float cw_b = cw[0];
            float h_b  = ch[1] - ch[0];
            float ch_b = ch[0];
            float d_b  = d[0];
            float d_p1 = d[1];
            #pragma unroll
            for (int k = 1; k < KD; ++k) {
                bool c = xc >= cw[k];
                w_b  = c ? (cw[k + 1] - cw[k]) : w_b;
                cw_b = c ? cw[k] : cw_b;
                h_b  = c ? (ch[k + 1] - ch[k]) : h_b;
                ch_b = c ? ch[k] : ch_b;
                d_b  = c ? d[k] : d_b;
                d_p1 = c ? d[k + 1] : d_p1;
            }

            float theta = (xc - cw_b) / w_b;
            float t1m   = theta * (1.0f - theta);
            float delta = h_b / w_b;
            float num   = h_b * (delta * theta * theta + d_b * t1m);
            float den   = delta + (d_b + d_p1 - 2.0f * delta) * t1m;
            float yv    = ch_b + num / den;
            bool inside = (xi >= -TBF) && (xi <= TBF);
            y[i] = inside ? yv : xi;
        } // i

        if (s < NSTACKC - 1) {
            #pragma unroll
            for (int j = 0; j < FD; ++j) x[j] = y[FD - 1 - j];
        } else {
            #pragma unroll
            for (int j = 0; j < FD; ++j) x[j] = y[j];
        }
    } // s

    {
        float4 o0 = make_float4(x[0], x[1], x[2], x[3]);
        float4 o1 = make_float4(x[4], x[5], x[6], x[7]);
        float4* op = (float4*)(OUT + (size_t)b * FD);
        op[0] = o0;
        op[1] = o1;
    }
}

extern "C" void kernel_launch(void* const* d_in, const int* in_sizes, int n_in,
                              void* d_out, int out_size, void* d_ws, size_t ws_size,
                              hipStream_t stream) {
    const float* X  = (const float*)d_in[0];
    const float* W0 = (const float*)d_in[1];
    const float* B0 = (const float*)d_in[2];
    const float* W1 = (const float*)d_in[3];
    const float* B1 = (const float*)d_in[4];
    const float* W2 = (const float*)d_in[5];
    const float* B2 = (const float*)d_in[6];
    float* OUT = (float*)d_out;

    int Bn = in_sizes[0] / FD;
    int threads = 256;
    int blocks = (Bn + threads - 1) / threads;
    hipLaunchKernelGGL(nsf_fused_kernel, dim3(blocks), dim3(threads), 0, stream,
                       X, W0, B0, W1, B1, W2, B2, OUT, Bn);
}

// Round 2
// 1801.486 us; speedup vs baseline: 1.8190x; 1.8190x over previous
//
#include <hip/hip_runtime.h>
#include <math.h>

#define NSTACKC 4
#define FD 8
#define HD 64
#define KD 10
#define MD 29
#define TBF 4.0f
#define ROWS 64      // rows per block (= lanes per wave)
#define LDSP 9       // padded LDS row stride (gcd(9,32)=1 -> conflict-free)
#define HCH 16       // h2 chunk size (caps VGPR pressure)

__device__ __forceinline__ float splus(float v) {
    // softplus: log1p(exp(v)), stable for large v
    return (v > 20.0f) ? v : log1pf(__expf(v));
}

__global__ __launch_bounds__(512, 4) void nsf_wavefeat_kernel(
    const float* __restrict__ X,
    const float* __restrict__ W0,
    const float* __restrict__ B0,
    const float* __restrict__ W1,
    const float* __restrict__ B1,
    const float* __restrict__ W2,
    const float* __restrict__ B2,
    float* __restrict__ OUT,
    int Bn)
{
    __shared__ float xs[ROWS * LDSP];

    const int t    = threadIdx.x;
    const int lane = t & 63;
    // wave id == feature index; force into SGPR so weight addrs are provably uniform
    const int wid  = __builtin_amdgcn_readfirstlane(t >> 6);
    const size_t rowbase = (size_t)blockIdx.x * ROWS;

    // cooperative slab load: thread t loads element t of the block's 512-float slab
    {
        int r = t >> 3, f = t & 7;
        float v = 0.0f;
        if (rowbase + r < (size_t)Bn) v = X[rowbase * FD + t];
        xs[r * LDSP + f] = v;
    }
    __syncthreads();

    for (int s = 0; s < NSTACKC; ++s) {
        // ---- read this stack's x (with reversal baked into the slot index) ----
        // stack 0 reads direct; stacks 1..3 read reversed (prev stack's y[::-1])
        float x[FD];
        #pragma unroll
        for (int f = 0; f < FD; ++f) {
            int slot = (s == 0) ? f : (FD - 1 - f);
            x[f] = xs[lane * LDSP + slot];
        }
        float xi = 0.0f;
        #pragma unroll
        for (int f = 0; f < FD; ++f) if (wid == f) xi = x[f];  // uniform selects
        __syncthreads();  // WAR: everyone done reading before y writes below

        const float* w0s = W0 + (((size_t)s * FD + wid) * FD) * HD;
        const float* b0s = B0 + ((size_t)s * FD + wid) * HD;
        const float* w1s = W1 + (((size_t)s * FD + wid) * HD) * HD;
        const float* b1s = B1 + ((size_t)s * FD + wid) * HD;
        const float* w2s = W2 + (((size_t)s * FD + wid) * HD) * MD;
        const float* b2s = B2 + ((size_t)s * FD + wid) * MD;

        // ---- layer 1: masked 8 -> 64, relu (mask is wave-uniform: f <= wid) ----
        float h1[HD];
        #pragma unroll
        for (int hh = 0; hh < HD; ++hh) h1[hh] = b0s[hh];
        #pragma unroll
        for (int f = 0; f < FD; ++f) {
            if (f <= wid) {  // scalar branch, skips whole 64-FMA block
                float xf = x[f];
                const float* wrow = w0s + f * HD;
                #pragma unroll
                for (int hh = 0; hh < HD; ++hh)
                    h1[hh] = fmaf(xf, wrow[hh], h1[hh]);
            }
        }
        #pragma unroll
        for (int hh = 0; hh < HD; ++hh) h1[hh] = fmaxf(h1[hh], 0.0f);

        // ---- layers 2+3 chunked: h2 in chunks of HCH to cap VGPR pressure ----
        float p[MD];
        #pragma unroll
        for (int m = 0; m < MD; ++m) p[m] = b2s[m];

        #pragma unroll
        for (int c = 0; c < HD / HCH; ++c) {
            float h2[HCH];
            #pragma unroll
            for (int j = 0; j < HCH; ++j) h2[j] = b1s[c * HCH + j];
            #pragma unroll
            for (int hh = 0; hh < HD; ++hh) {
                float hv = h1[hh];
                const float* wrow = w1s + hh * HD + c * HCH;
                #pragma unroll
                for (int j = 0; j < HCH; ++j)
                    h2[j] = fmaf(hv, wrow[j], h2[j]);
            }
            #pragma unroll
            for (int j = 0; j < HCH; ++j) {
                float hv = fmaxf(h2[j], 0.0f);
                const float* wrow = w2s + (c * HCH + j) * MD;
                #pragma unroll
                for (int m = 0; m < MD; ++m)
                    p[m] = fmaf(hv, wrow[m], p[m]);
            }
        }

        // ---- rational-quadratic spline on feature wid ----
        // widths
        float mw = p[0];
        #pragma unroll
        for (int k = 1; k < KD; ++k) mw = fmaxf(mw, p[k]);
        float ew[KD];
        float sw = 0.0f;
        #pragma unroll
        for (int k = 0; k < KD; ++k) { ew[k] = __expf(p[k] - mw); sw += ew[k]; }
        float invw = 1.0f / sw;
        float cw[KD + 1];
        cw[0] = -TBF;
        {
            float acc = 0.0f;
            #pragma unroll
            for (int k = 0; k < KD; ++k) {
                float wk = 0.001f + (1.0f - 0.001f * KD) * ew[k] * invw;
                acc += wk;
                cw[k + 1] = 2.0f * TBF * acc - TBF;
            }
        }
        cw[KD] = TBF;

        // heights
        float mh = p[KD];
        #pragma unroll
        for (int k = 1; k < KD; ++k) mh = fmaxf(mh, p[KD + k]);
        float eh[KD];
        float sh = 0.0f;
        #pragma unroll
        for (int k = 0; k < KD; ++k) { eh[k] = __expf(p[KD + k] - mh); sh += eh[k]; }
        float invh = 1.0f / sh;
        float ch[KD + 1];
        ch[0] = -TBF;
        {
            float acc = 0.0f;
            #pragma unroll
            for (int k = 0; k < KD; ++k) {
                float hk = 0.001f + (1.0f - 0.001f * KD) * eh[k] * invh;
                acc += hk;
                ch[k + 1] = 2.0f * TBF * acc - TBF;
            }
        }
        ch[KD] = TBF;

        // derivatives: d[0]=d[10]=MIN_D+softplus(const)==1.0 exactly
        float d[KD + 1];
        d[0] = 1.0f;
        d[KD] = 1.0f;
        #pragma unroll
        for (int k = 1; k < KD; ++k) d[k] = 0.001f + splus(p[2 * KD + (k - 1)]);

        float xc = fminf(fmaxf(xi, -TBF), TBF);

        // bin select: monotone cndmask chain
        float w_b  = cw[1] - cw[0];
        float cw_b = cw[0];
        float h_b  = ch[1] - ch[0];
        float ch_b = ch[0];
        float d_b  = d[0];
        float d_p1 = d[1];
        #pragma unroll
        for (int k = 1; k < KD; ++k) {
            bool c = xc >= cw[k];
            w_b  = c ? (cw[k + 1] - cw[k]) : w_b;
            cw_b = c ? cw[k] : cw_b;
            h_b  = c ? (ch[k + 1] - ch[k]) : h_b;
            ch_b = c ? ch[k] : ch_b;
            d_b  = c ? d[k] : d_b;
            d_p1 = c ? d[k + 1] : d_p1;
        }

        float theta = (xc - cw_b) / w_b;
        float t1m   = theta * (1.0f - theta);
        float delta = h_b / w_b;
        float num   = h_b * (delta * theta * theta + d_b * t1m);
        float den   = delta + (d_b + d_p1 - 2.0f * delta) * t1m;
        float yv    = ch_b + num / den;
        bool inside = (xi >= -TBF) && (xi <= TBF);
        float y = inside ? yv : xi;

        // ---- write y to its feature slot (direct; reversal handled on read) ----
        xs[lane * LDSP + wid] = y;
        __syncthreads();
    } // s

    // coalesced store of final slab
    {
        int r = t >> 3, f = t & 7;
        if (rowbase + r < (size_t)Bn)
            OUT[rowbase * FD + t] = xs[r * LDSP + f];
    }
}

extern "C" void kernel_launch(void* const* d_in, const int* in_sizes, int n_in,
                              void* d_out, int out_size, void* d_ws, size_t ws_size,
                              hipStream_t stream) {
    const float* X  = (const float*)d_in[0];
    const float* W0 = (const float*)d_in[1];
    const float* B0 = (const float*)d_in[2];
    const float* W1 = (const float*)d_in[3];
    const float* B1 = (const float*)d_in[4];
    const float* W2 = (const float*)d_in[5];
    const float* B2 = (const float*)d_in[6];
    float* OUT = (float*)d_out;

    int Bn = in_sizes[0] / FD;
    int blocks = (Bn + ROWS - 1) / ROWS;
    hipLaunchKernelGGL(nsf_wavefeat_kernel, dim3(blocks), dim3(512), 0, stream,
                       X, W0, B0, W1, B1, W2, B2, OUT, Bn);
}